// Round 1
// baseline (271.934 us; speedup 1.0000x reference)
//
#include <hip/hip_runtime.h>
#include <hip/hip_bf16.h>
#include <math.h>
#include <stdint.h>

#define N_TOKENS 16384
#define DIM 4096
#define NEXP 64

typedef const __attribute__((address_space(1))) void gvoid_t;
typedef __attribute__((address_space(3))) void svoid_t;

constexpr int MT = 128;  // tokens per block (K1)
constexpr int KC = 128;  // k-chunk staged per iteration
constexpr int TM = 4;    // tokens per thread
constexpr int TN = 8;    // experts per thread

// ---------------- K1: logits = x @ W^T (fp32, K-split partials) ----------------
__global__ __launch_bounds__(256) void k1_gemm(const float* __restrict__ x,
                                               const float* __restrict__ W,
                                               float* __restrict__ P, int KS) {
  __shared__ float wlds[NEXP * KC];  // [e][kk], 32 KB
  const int tid = threadIdx.x;
  const int tg = tid & 31;   // token group (interleaved tokens tg + 32*i)
  const int eg = tid >> 5;   // expert group (8 experts each)
  const int tok0 = blockIdx.x * MT;
  const int k0 = blockIdx.y * KS;

  float2 acc2[TM][TN];
#pragma unroll
  for (int i = 0; i < TM; ++i)
#pragma unroll
    for (int j = 0; j < TN; ++j) acc2[i][j] = make_float2(0.f, 0.f);

  for (int kc = 0; kc < KS; kc += KC) {
    __syncthreads();  // protect wlds from previous iteration's readers
    // stage W[0:64][k0+kc : +KC] -> wlds, 8 x global_load_lds dwordx4
#pragma unroll
    for (int c = 0; c < (NEXP * KC) / (256 * 4); ++c) {
      const int f = c * 1024 + tid * 4;  // float index in chunk
      const int e = f >> 7;              // / KC
      const int kk = f & (KC - 1);
      const float* src = W + (size_t)e * DIM + (k0 + kc + kk);
      float* dstg = wlds + c * 1024 + (tid >> 6) * 256;  // wave-uniform base
      __builtin_amdgcn_global_load_lds((gvoid_t*)src, (svoid_t*)dstg, 16, 0, 0);
    }
    __syncthreads();  // compiler drains vmcnt before barrier

    const float* xr[TM];
#pragma unroll
    for (int i = 0; i < TM; ++i)
      xr[i] = x + (size_t)(tok0 + tg + 32 * i) * DIM + (k0 + kc);

#pragma unroll 4
    for (int kk = 0; kk < KC; kk += 4) {
      float4 wv[TN];
#pragma unroll
      for (int j = 0; j < TN; ++j)
        wv[j] = *(const float4*)(wlds + (eg * TN + j) * KC + kk);
#pragma unroll
      for (int i = 0; i < TM; ++i) {
        const float4 xv = *(const float4*)(xr[i] + kk);
#pragma unroll
        for (int j = 0; j < TN; ++j) {
          acc2[i][j].x = fmaf(xv.x, wv[j].x, acc2[i][j].x);
          acc2[i][j].y = fmaf(xv.y, wv[j].y, acc2[i][j].y);
          acc2[i][j].x = fmaf(xv.z, wv[j].z, acc2[i][j].x);
          acc2[i][j].y = fmaf(xv.w, wv[j].w, acc2[i][j].y);
        }
      }
    }
  }

  // write partial logits
#pragma unroll
  for (int i = 0; i < TM; ++i) {
    const int tok = tok0 + tg + 32 * i;
    float* prow = P + ((size_t)blockIdx.y * N_TOKENS + tok) * NEXP + eg * TN;
    float4 o0, o1;
    o0.x = acc2[i][0].x + acc2[i][0].y;
    o0.y = acc2[i][1].x + acc2[i][1].y;
    o0.z = acc2[i][2].x + acc2[i][2].y;
    o0.w = acc2[i][3].x + acc2[i][3].y;
    o1.x = acc2[i][4].x + acc2[i][4].y;
    o1.y = acc2[i][5].x + acc2[i][5].y;
    o1.z = acc2[i][6].x + acc2[i][6].y;
    o1.w = acc2[i][7].x + acc2[i][7].y;
    *(float4*)prow = o0;
    *(float4*)(prow + 4) = o1;
  }
}

// ------------- K2: sum partials, softmax, top-2, chunk histograms -------------
__global__ __launch_bounds__(128) void k2_softmax_top2(const float* __restrict__ P,
                                                       int split,
                                                       float* __restrict__ topw,
                                                       int* __restrict__ sel,
                                                       int* __restrict__ cnt) {
  __shared__ int hist[NEXP];
  const int tid = threadIdx.x;
  const int t = blockIdx.x * 128 + tid;
  if (tid < NEXP) hist[tid] = 0;
  __syncthreads();

  float4 v[16];
  {
    const float* row = P + (size_t)t * NEXP;
#pragma unroll
    for (int c = 0; c < 16; ++c) v[c] = *(const float4*)(row + c * 4);
  }
  for (int s = 1; s < split; ++s) {
    const float* row = P + ((size_t)s * N_TOKENS + t) * NEXP;
#pragma unroll
    for (int c = 0; c < 16; ++c) {
      const float4 u = *(const float4*)(row + c * 4);
      v[c].x += u.x; v[c].y += u.y; v[c].z += u.z; v[c].w += u.w;
    }
  }

  float v0 = -INFINITY, v1 = -INFINITY;
  int i0 = 0, i1 = 0;
#define TOP2_STEP(val, idx)                                   \
  {                                                           \
    const float vv = (val);                                   \
    const int ee = (idx);                                     \
    if (vv > v0) { v1 = v0; i1 = i0; v0 = vv; i0 = ee; }      \
    else if (vv > v1) { v1 = vv; i1 = ee; }                   \
  }
#pragma unroll
  for (int c = 0; c < 16; ++c) {
    TOP2_STEP(v[c].x, c * 4 + 0);
    TOP2_STEP(v[c].y, c * 4 + 1);
    TOP2_STEP(v[c].z, c * 4 + 2);
    TOP2_STEP(v[c].w, c * 4 + 3);
  }
#undef TOP2_STEP

  float denom = 0.f;
#pragma unroll
  for (int c = 0; c < 16; ++c) {
    denom += expf(v[c].x - v0);
    denom += expf(v[c].y - v0);
    denom += expf(v[c].z - v0);
    denom += expf(v[c].w - v0);
  }
  const float w0 = 1.0f / denom;           // expf(0) == 1 exactly
  const float w1 = expf(v1 - v0) / denom;

  topw[t * 2 + 0] = w0;
  topw[t * 2 + 1] = w1;
  sel[t * 2 + 0] = i0;
  sel[t * 2 + 1] = i1;
  atomicAdd(&hist[i0], 1);
  atomicAdd(&hist[i1], 1);
  __syncthreads();
  if (tid < NEXP) cnt[blockIdx.x * NEXP + tid] = hist[tid];
}

// -------- K3: expert totals (counts out), exclusive offsets, chunk bases --------
__global__ void k3_scan(const int* __restrict__ cnt, int* __restrict__ cb,
                        float* __restrict__ counts_out) {
  __shared__ int tot[NEXP];
  const int e = threadIdx.x;  // 64 threads
  int run = 0;
  for (int p = 0; p < 128; ++p) run += cnt[p * NEXP + e];
  tot[e] = run;
  counts_out[e] = (float)run;
  __syncthreads();
  int g = 0;
  for (int q = 0; q < e; ++q) g += tot[q];
  int r = g;
  for (int p = 0; p < 128; ++p) {
    cb[p * NEXP + e] = r;
    r += cnt[p * NEXP + e];
  }
}

// ---------------- K4: stable scatter (counting-sort permutation) ----------------
__global__ __launch_bounds__(256) void k4_scatter(const int* __restrict__ sel,
                                                  const int* __restrict__ cb,
                                                  float* __restrict__ gout) {
  __shared__ int wcnt[4 * NEXP];
  const int tid = threadIdx.x;
  const int s = blockIdx.x * 256 + tid;
  const int e = sel[s];
  const int lane = tid & 63;
  const int wv = tid >> 6;
  wcnt[tid] = 0;
  __syncthreads();

  unsigned long long mask = ~0ull;
#pragma unroll
  for (int b = 0; b < 6; ++b) {
    const unsigned long long bb = __ballot((e >> b) & 1);
    mask &= ((e >> b) & 1) ? bb : ~bb;
  }
  const unsigned long long below = mask & ((1ull << lane) - 1ull);
  const int wr = __popcll(below);
  if (wr == 0) wcnt[wv * NEXP + e] = __popcll(mask);
  __syncthreads();

  int base = cb[blockIdx.x * NEXP + e];
  for (int w2 = 0; w2 < wv; ++w2) base += wcnt[w2 * NEXP + e];
  gout[base + wr] = (float)s;
}

extern "C" void kernel_launch(void* const* d_in, const int* in_sizes, int n_in,
                              void* d_out, int out_size, void* d_ws, size_t ws_size,
                              hipStream_t stream) {
  const float* x = (const float*)d_in[0];
  const float* W = (const float*)d_in[1];
  float* out = (float*)d_out;

  auto need = [](int s) {
    return (size_t)s * N_TOKENS * NEXP * 4 + (size_t)N_TOKENS * 2 * 4 +
           2 * (size_t)128 * NEXP * 4;
  };
  int split = 4;
  if (ws_size < need(4)) split = (ws_size >= need(2)) ? 2 : 1;
  const int KS = DIM / split;

  float* P = (float*)d_ws;
  int* sel = (int*)((char*)d_ws + (size_t)split * N_TOKENS * NEXP * 4);
  int* cnt = sel + N_TOKENS * 2;
  int* cb = cnt + 128 * NEXP;

  hipLaunchKernelGGL(k1_gemm, dim3(N_TOKENS / MT, split), dim3(256), 0, stream,
                     x, W, P, KS);
  hipLaunchKernelGGL(k2_softmax_top2, dim3(N_TOKENS / 128), dim3(128), 0, stream,
                     P, split, out, sel, cnt);
  hipLaunchKernelGGL(k3_scan, dim3(1), dim3(64), 0, stream, cnt, cb,
                     out + 2 * N_TOKENS + 2 * N_TOKENS);
  hipLaunchKernelGGL(k4_scatter, dim3((2 * N_TOKENS) / 256), dim3(256), 0, stream,
                     sel, cb, out + 2 * N_TOKENS);
}